// Round 1
// baseline (830.069 us; speedup 1.0000x reference)
//
#include <hip/hip_runtime.h>
#include <hip/hip_bf16.h>

// GLIFR forward, MI355X. Structure:
//   S(T,B,H) f32 = x @ W_iv            (GEMM, bf16 in / f32 out)
//   for chunk c in 0..9 (20 steps each == DELAY):
//     if c>0: S[chunk c] += F[chunk c-1] @ W_lat   (GEMM, beta=1)
//     recurrence kernel: per-(b,h) ASC/voltage/firing over 20 steps -> F bf16
//   out(B,T,O) = F @ w_out + b_out     (GEMM, bias)
// Requires ~185 MB of d_ws.

#define B_ 64
#define T_ 200
#define I_ 512
#define H_ 2048
#define O_ 512
#define BH_ 131072          // B_*H_
#define DELAY_ 20
#define DT_ 0.05f
#define RMEM_ 0.1f

typedef __bf16 bf16x8 __attribute__((ext_vector_type(8)));
typedef float f32x4 __attribute__((ext_vector_type(4)));

__device__ __forceinline__ unsigned short f2bf(float f) {
    unsigned int u = __builtin_bit_cast(unsigned int, f);
    u = (u + 0x7fff + ((u >> 16) & 1)) >> 16;
    return (unsigned short)u;
}

// ---------- f32 -> bf16 (same layout), 4 elems/thread ----------
__global__ void k_cvt4(const float* __restrict__ in, unsigned short* __restrict__ out, int n4) {
    int i = blockIdx.x * 256 + threadIdx.x;
    if (i >= n4) return;
    float4 v = ((const float4*)in)[i];
    ushort4 o;
    o.x = f2bf(v.x); o.y = f2bf(v.y); o.z = f2bf(v.z); o.w = f2bf(v.w);
    ((ushort4*)out)[i] = o;
}

// ---------- f32 (R x C) -> bf16 transposed (C x R) ----------
__global__ void k_tcvt(const float* __restrict__ in, unsigned short* __restrict__ out, int R, int C) {
    int i = blockIdx.x * 256 + threadIdx.x;
    if (i >= R * C) return;
    int r = i / C, c = i - r * C;
    out[c * R + r] = f2bf(in[i]);
}

// ---------- bf16 GEMM: C(MxN) = A(MxK) * Bt(NxK)^T  [+ C][+ bias] ----------
// 128x128 tile, BK=32, 4 waves, 16x16x32 MFMA. Row maps:
//   map==1: m -> (m&63)*200 + (m>>6)   ((t,b) index -> (b,t) row)
__global__ __launch_bounds__(256) void k_gemm(
    const unsigned short* __restrict__ A, const unsigned short* __restrict__ Bt,
    float* __restrict__ C, const float* __restrict__ bias,
    int M, int N, int K, int lda, int ldc, int amap, int cmap, int beta)
{
    __shared__ unsigned short As[128][56];   // 32 used + 24 pad (112B rows, 16B aligned)
    __shared__ unsigned short Bs[128][56];

    const int tid = threadIdx.x;
    const int bm = blockIdx.y, bn = blockIdx.x;
    const int lane = tid & 63, wave = tid >> 6;
    const int wr = (wave >> 1) * 64, wc = (wave & 1) * 64;
    const int fr = lane & 15, kg = lane >> 4;

    f32x4 acc[4][4] = {};
    const int nk = K >> 5;

    for (int kt = 0; kt < nk; ++kt) {
        // stage: 128 rows x 4 chunks of 16B each, for A and Bt
        #pragma unroll
        for (int it = 0; it < 2; ++it) {
            int ch = tid + it * 256;          // 0..511
            int row = ch >> 2, cc = ch & 3;
            int gm = bm * 128 + row;
            int ar = (amap == 1) ? ((gm & 63) * 200 + (gm >> 6)) : gm;
            *(uint4*)(&As[row][cc * 8]) = *(const uint4*)(A + (size_t)ar * lda + kt * 32 + cc * 8);
            int gn = bn * 128 + row;
            *(uint4*)(&Bs[row][cc * 8]) = *(const uint4*)(Bt + (size_t)gn * K + kt * 32 + cc * 8);
        }
        __syncthreads();

        bf16x8 af[4], bfr[4];
        #pragma unroll
        for (int i = 0; i < 4; ++i) {
            af[i]  = *(const bf16x8*)(&As[wr + i * 16 + fr][kg * 8]);
            bfr[i] = *(const bf16x8*)(&Bs[wc + i * 16 + fr][kg * 8]);
        }
        #pragma unroll
        for (int i = 0; i < 4; ++i)
            #pragma unroll
            for (int j = 0; j < 4; ++j)
                acc[i][j] = __builtin_amdgcn_mfma_f32_16x16x32_bf16(af[i], bfr[j], acc[i][j], 0, 0, 0);
        __syncthreads();
    }

    // epilogue: C/D layout col = lane&15, row = (lane>>4)*4 + reg
    #pragma unroll
    for (int i = 0; i < 4; ++i) {
        int rbase = bm * 128 + wr + i * 16 + kg * 4;
        #pragma unroll
        for (int j = 0; j < 4; ++j) {
            int col = bn * 128 + wc + j * 16 + fr;
            #pragma unroll
            for (int r = 0; r < 4; ++r) {
                int m = rbase + r;
                int cr = (cmap == 1) ? ((m & 63) * 200 + (m >> 6)) : m;
                float* cp = C + (size_t)cr * ldc + col;
                float v = acc[i][j][r];
                if (beta) v += *cp;
                if (bias) v += bias[col];
                *cp = v;
            }
        }
    }
}

// ---------- per-(b,h) recurrence over one chunk of nsteps ----------
__global__ __launch_bounds__(256) void k_rec(
    const float* __restrict__ S, unsigned short* __restrict__ F,
    float* __restrict__ volt, float* __restrict__ fire, float* __restrict__ asc,
    const float* __restrict__ thresh, const float* __restrict__ km,
    const float* __restrict__ asc_amp, const float* __restrict__ asc_r,
    const float* __restrict__ asc_k, int t0, int nsteps)
{
    int idx = blockIdx.x * 256 + threadIdx.x;   // b*H + h
    int h = idx & (H_ - 1);
    float v = volt[idx], f = fire[idx];
    float a0 = asc[idx], a1 = asc[BH_ + idx];
    float th = thresh[h], k = km[h];
    float amp0 = asc_amp[h], amp1 = asc_amp[H_ + h];
    float r0 = asc_r[h], r1 = asc_r[H_ + h];
    float d0 = expf(-DT_ * asc_k[h]), d1 = expf(-DT_ * asc_k[H_ + h]);
    const float dtk = DT_ * k;
    for (int t = 0; t < nsteps; ++t) {
        float syn = S[(size_t)(t0 + t) * BH_ + idx];
        float na0 = a0 * d0 + f * (r0 * a0 + amp0);
        float na1 = a1 * d1 + f * (r1 * a1 + amp1);
        a0 = na0; a1 = na1;
        float tot = syn + a0 + a1;
        v = v * (1.f - f);
        v = v + dtk * (RMEM_ * tot - v);
        f = 1.f / (1.f + expf(-(v - th)));
        F[(size_t)(t0 + t) * BH_ + idx] = f2bf(f);
    }
    volt[idx] = v; fire[idx] = f;
    asc[idx] = a0; asc[BH_ + idx] = a1;
}

extern "C" void kernel_launch(void* const* d_in, const int* in_sizes, int n_in,
                              void* d_out, int out_size, void* d_ws, size_t ws_size,
                              hipStream_t stream) {
    const float* x       = (const float*)d_in[0];
    const float* w_iv    = (const float*)d_in[1];
    const float* w_lat   = (const float*)d_in[2];
    const float* thresh  = (const float*)d_in[3];
    const float* km      = (const float*)d_in[4];
    const float* asc_amp = (const float*)d_in[5];
    const float* asc_r   = (const float*)d_in[6];
    const float* asc_k   = (const float*)d_in[7];
    const float* w_out   = (const float*)d_in[8];
    const float* b_out   = (const float*)d_in[9];
    float* out = (float*)d_out;

    char* ws = (char*)d_ws;
    float*          S     = (float*)ws;                                   // 104,857,600 B  (T,B,H) f32
    unsigned short* Fb    = (unsigned short*)(ws + 104857600);            //  52,428,800 B  (T,B,H) bf16
    unsigned short* xb    = (unsigned short*)(ws + 157286400);            //  13,107,200 B  x bf16
    unsigned short* WivT  = (unsigned short*)(ws + 170393600);            //   2,097,152 B  (H,I) bf16
    unsigned short* WlatT = (unsigned short*)(ws + 172490752);            //   8,388,608 B  (H,H) bf16
    unsigned short* WoutT = (unsigned short*)(ws + 180879360);            //   2,097,152 B  (O,H) bf16
    float*          volt  = (float*)(ws + 182976512);                     //     524,288 B
    float*          fire  = (float*)(ws + 183500800);                     //     524,288 B
    float*          asc   = (float*)(ws + 184025088);                     //   1,048,576 B

    // conversions
    k_cvt4<<<6400, 256, 0, stream>>>(x, xb, (B_ * T_ * I_) / 4);
    k_tcvt<<<4096, 256, 0, stream>>>(w_iv, WivT, I_, H_);
    k_tcvt<<<16384, 256, 0, stream>>>(w_lat, WlatT, H_, H_);
    k_tcvt<<<4096, 256, 0, stream>>>(w_out, WoutT, H_, O_);

    // S = x @ W_iv   (M=12800 rows in (t,b) order; A rows come from x in (b,t) order)
    k_gemm<<<dim3(H_ / 128, (B_ * T_) / 128), 256, 0, stream>>>(
        xb, WivT, S, nullptr, B_ * T_, H_, I_, I_, H_, 1, 0, 0);

    // zero state (volt, fire, asc are contiguous)
    hipMemsetAsync(volt, 0, 524288 + 524288 + 1048576, stream);

    for (int c = 0; c < T_ / DELAY_; ++c) {
        if (c) {
            k_gemm<<<dim3(H_ / 128, (DELAY_ * B_) / 128), 256, 0, stream>>>(
                Fb + (size_t)(c - 1) * DELAY_ * BH_, WlatT,
                S + (size_t)c * DELAY_ * BH_, nullptr,
                DELAY_ * B_, H_, H_, H_, H_, 0, 0, 1);
        }
        k_rec<<<BH_ / 256, 256, 0, stream>>>(S, Fb, volt, fire, asc,
                                             thresh, km, asc_amp, asc_r, asc_k,
                                             c * DELAY_, DELAY_);
    }

    // out = F @ w_out + b_out   (C rows remapped (t,b) -> (b,t))
    k_gemm<<<dim3(O_ / 128, (B_ * T_) / 128), 256, 0, stream>>>(
        Fb, WoutT, out, b_out, B_ * T_, O_, H_, H_, O_, 0, 1, 0);
}

// Round 2
// 733.209 us; speedup vs baseline: 1.1321x; 1.1321x over previous
//
#include <hip/hip_runtime.h>
#include <hip/hip_bf16.h>

// GLIFR forward, MI355X. Structure:
//   S(T,B,H) f32 = x @ W_iv            (GEMM, bf16 in / f32 out)
//   for chunk c in 0..9 (20 steps each == DELAY):
//     if c>0: S[chunk c] += F[chunk c-1] @ W_lat   (GEMM, beta=1)
//     recurrence kernel: per-(b,h) ASC/voltage/firing over 20 steps -> F bf16
//   out(B,T,O) = F @ w_out + b_out     (GEMM, bias)
// GEMM is the m97 structure: 128x128 tile, BK=32, 4 waves, global_load_lds
// width-16 into linear LDS, XCD-aware bijective block swizzle.

#define B_ 64
#define T_ 200
#define I_ 512
#define H_ 2048
#define O_ 512
#define BH_ 131072          // B_*H_
#define DELAY_ 20
#define DT_ 0.05f
#define RMEM_ 0.1f

typedef __bf16 bf16x8 __attribute__((ext_vector_type(8)));
typedef float f32x4 __attribute__((ext_vector_type(4)));

__device__ __forceinline__ unsigned short f2bf(float f) {
    unsigned int u = __builtin_bit_cast(unsigned int, f);
    u = (u + 0x7fff + ((u >> 16) & 1)) >> 16;
    return (unsigned short)u;
}

__device__ __forceinline__ void gload16(const void* g, void* l) {
    __builtin_amdgcn_global_load_lds(
        (const __attribute__((address_space(1))) unsigned int*)g,
        (__attribute__((address_space(3))) unsigned int*)l, 16, 0, 0);
}

// ---------- f32 -> bf16 (same layout), 4 elems/thread ----------
__global__ void k_cvt4(const float* __restrict__ in, unsigned short* __restrict__ out, int n4) {
    int i = blockIdx.x * 256 + threadIdx.x;
    if (i >= n4) return;
    float4 v = ((const float4*)in)[i];
    ushort4 o;
    o.x = f2bf(v.x); o.y = f2bf(v.y); o.z = f2bf(v.z); o.w = f2bf(v.w);
    ((ushort4*)out)[i] = o;
}

// ---------- f32 (R x C) -> bf16 transposed (C x R), 32x32 LDS tiles ----------
__global__ __launch_bounds__(256) void k_tcvt(const float* __restrict__ in,
                                              unsigned short* __restrict__ out, int R, int C) {
    __shared__ float t[32][33];
    int bx = blockIdx.x, by = blockIdx.y;
    int tx = threadIdx.x & 31, ty = threadIdx.x >> 5;   // 32 x 8
    #pragma unroll
    for (int r = 0; r < 32; r += 8)
        t[ty + r][tx] = in[(size_t)(by * 32 + ty + r) * C + bx * 32 + tx];
    __syncthreads();
    #pragma unroll
    for (int r = 0; r < 32; r += 8)
        out[(size_t)(bx * 32 + ty + r) * R + by * 32 + tx] = f2bf(t[tx][ty + r]);
}

// ---------- bf16 GEMM: C(MxN) = A(MxK) * Bt(NxK)^T  [+ C][+ bias] ----------
// amap/cmap==1: m -> (m&63)*200 + (m>>6)   ((t,b) index -> (b,t) row)
// 1D grid of gx*gy blocks; bijective XCD swizzle; fast axis = min(gx,gy).
__global__ __launch_bounds__(256) void k_gemm(
    const unsigned short* __restrict__ A, const unsigned short* __restrict__ Bt,
    float* __restrict__ C, const float* __restrict__ bias,
    int M, int N, int K, int lda, int ldc, int amap, int cmap, int beta,
    int gx, int gy)
{
    __shared__ unsigned short As[128 * 32];
    __shared__ unsigned short Bs[128 * 32];

    const int nb = gx * gy;
    const int hw = blockIdx.x;
    const int wid = (hw & 7) * (nb >> 3) + (hw >> 3);   // XCD k -> contiguous chunk
    int bm, bn;
    if (gx <= gy) { bn = wid % gx; bm = wid / gx; }
    else          { bm = wid % gy; bn = wid / gy; }

    const int tid = threadIdx.x;
    const int lane = tid & 63, wave = tid >> 6;
    const int wr = (wave >> 1) * 64, wc = (wave & 1) * 64;
    const int fr = lane & 15, kg = lane >> 4;

    // staging: thread stages 16B chunks tid and tid+256 (rows r0, r0+64)
    const int r0 = tid >> 2, c0 = tid & 3;
    const int gm0 = bm * 128 + r0, gm1 = gm0 + 64;
    const size_t ar0 = (size_t)((amap == 1) ? ((gm0 & 63) * 200 + (gm0 >> 6)) : gm0) * lda + c0 * 8;
    const size_t ar1 = (size_t)((amap == 1) ? ((gm1 & 63) * 200 + (gm1 >> 6)) : gm1) * lda + c0 * 8;
    const size_t br0 = (size_t)(bn * 128 + r0) * K + c0 * 8;
    const size_t br1 = br0 + (size_t)64 * K;

    f32x4 acc[4][4] = {};
    const int nk = K >> 5;

    for (int kt = 0; kt < nk; ++kt) {
        const int ko = kt * 32;
        gload16(A + ar0 + ko, &As[(size_t)tid * 8]);
        gload16(A + ar1 + ko, &As[(size_t)(tid + 256) * 8]);
        gload16(Bt + br0 + ko, &Bs[(size_t)tid * 8]);
        gload16(Bt + br1 + ko, &Bs[(size_t)(tid + 256) * 8]);
        __syncthreads();

        bf16x8 af[4], bfr[4];
        #pragma unroll
        for (int i = 0; i < 4; ++i) {
            af[i]  = *(const bf16x8*)(&As[(wr + i * 16 + fr) * 32 + kg * 8]);
            bfr[i] = *(const bf16x8*)(&Bs[(wc + i * 16 + fr) * 32 + kg * 8]);
        }
        #pragma unroll
        for (int i = 0; i < 4; ++i)
            #pragma unroll
            for (int j = 0; j < 4; ++j)
                acc[i][j] = __builtin_amdgcn_mfma_f32_16x16x32_bf16(af[i], bfr[j], acc[i][j], 0, 0, 0);
        __syncthreads();
    }

    // epilogue: C/D layout col = lane&15, row = (lane>>4)*4 + reg
    #pragma unroll
    for (int i = 0; i < 4; ++i) {
        int rbase = bm * 128 + wr + i * 16 + kg * 4;
        #pragma unroll
        for (int j = 0; j < 4; ++j) {
            int col = bn * 128 + wc + j * 16 + fr;
            #pragma unroll
            for (int r = 0; r < 4; ++r) {
                int m = rbase + r;
                int cr = (cmap == 1) ? ((m & 63) * 200 + (m >> 6)) : m;
                float* cp = C + (size_t)cr * ldc + col;
                float v = acc[i][j][r];
                if (beta) v += *cp;
                if (bias) v += bias[col];
                *cp = v;
            }
        }
    }
}

// ---------- per-(b,h) recurrence over one chunk of nsteps ----------
__global__ __launch_bounds__(256) void k_rec(
    const float* __restrict__ S, unsigned short* __restrict__ F,
    float* __restrict__ volt, float* __restrict__ fire, float* __restrict__ asc,
    const float* __restrict__ thresh, const float* __restrict__ km,
    const float* __restrict__ asc_amp, const float* __restrict__ asc_r,
    const float* __restrict__ asc_k, int t0, int nsteps)
{
    int idx = blockIdx.x * 256 + threadIdx.x;   // b*H + h
    int h = idx & (H_ - 1);
    float v = volt[idx], f = fire[idx];
    float a0 = asc[idx], a1 = asc[BH_ + idx];
    float th = thresh[h], k = km[h];
    float amp0 = asc_amp[h], amp1 = asc_amp[H_ + h];
    float r0 = asc_r[h], r1 = asc_r[H_ + h];
    float d0 = expf(-DT_ * asc_k[h]), d1 = expf(-DT_ * asc_k[H_ + h]);
    const float dtk = DT_ * k;
    for (int t = 0; t < nsteps; ++t) {
        float syn = S[(size_t)(t0 + t) * BH_ + idx];
        float na0 = a0 * d0 + f * (r0 * a0 + amp0);
        float na1 = a1 * d1 + f * (r1 * a1 + amp1);
        a0 = na0; a1 = na1;
        float tot = syn + a0 + a1;
        v = v * (1.f - f);
        v = v + dtk * (RMEM_ * tot - v);
        f = 1.f / (1.f + expf(-(v - th)));
        F[(size_t)(t0 + t) * BH_ + idx] = f2bf(f);
    }
    volt[idx] = v; fire[idx] = f;
    asc[idx] = a0; asc[BH_ + idx] = a1;
}

extern "C" void kernel_launch(void* const* d_in, const int* in_sizes, int n_in,
                              void* d_out, int out_size, void* d_ws, size_t ws_size,
                              hipStream_t stream) {
    const float* x       = (const float*)d_in[0];
    const float* w_iv    = (const float*)d_in[1];
    const float* w_lat   = (const float*)d_in[2];
    const float* thresh  = (const float*)d_in[3];
    const float* km      = (const float*)d_in[4];
    const float* asc_amp = (const float*)d_in[5];
    const float* asc_r   = (const float*)d_in[6];
    const float* asc_k   = (const float*)d_in[7];
    const float* w_out   = (const float*)d_in[8];
    const float* b_out   = (const float*)d_in[9];
    float* out = (float*)d_out;

    char* ws = (char*)d_ws;
    float*          S     = (float*)ws;                                   // (T,B,H) f32
    unsigned short* Fb    = (unsigned short*)(ws + 104857600);            // (T,B,H) bf16
    unsigned short* xb    = (unsigned short*)(ws + 157286400);            // x bf16
    unsigned short* WivT  = (unsigned short*)(ws + 170393600);            // (H,I) bf16
    unsigned short* WlatT = (unsigned short*)(ws + 172490752);            // (H,H) bf16
    unsigned short* WoutT = (unsigned short*)(ws + 180879360);            // (O,H) bf16
    float*          volt  = (float*)(ws + 182976512);
    float*          fire  = (float*)(ws + 183500800);
    float*          asc   = (float*)(ws + 184025088);

    // conversions
    k_cvt4<<<6400, 256, 0, stream>>>(x, xb, (B_ * T_ * I_) / 4);
    k_tcvt<<<dim3(H_ / 32, I_ / 32), 256, 0, stream>>>(w_iv, WivT, I_, H_);
    k_tcvt<<<dim3(H_ / 32, H_ / 32), 256, 0, stream>>>(w_lat, WlatT, H_, H_);
    k_tcvt<<<dim3(O_ / 32, H_ / 32), 256, 0, stream>>>(w_out, WoutT, H_, O_);

    // S = x @ W_iv   (rows (t,b); A rows gathered from x in (b,t) order)
    k_gemm<<<(B_ * T_ / 128) * (H_ / 128), 256, 0, stream>>>(
        xb, WivT, S, nullptr, B_ * T_, H_, I_, I_, H_, 1, 0, 0, H_ / 128, B_ * T_ / 128);

    // zero state (volt, fire, asc contiguous)
    hipMemsetAsync(volt, 0, 524288 + 524288 + 1048576, stream);

    for (int c = 0; c < T_ / DELAY_; ++c) {
        if (c) {
            k_gemm<<<(DELAY_ * B_ / 128) * (H_ / 128), 256, 0, stream>>>(
                Fb + (size_t)(c - 1) * DELAY_ * BH_, WlatT,
                S + (size_t)c * DELAY_ * BH_, nullptr,
                DELAY_ * B_, H_, H_, H_, H_, 0, 0, 1, H_ / 128, DELAY_ * B_ / 128);
        }
        k_rec<<<BH_ / 256, 256, 0, stream>>>(S, Fb, volt, fire, asc,
                                             thresh, km, asc_amp, asc_r, asc_k,
                                             c * DELAY_, DELAY_);
    }

    // out = F @ w_out + b_out   (C rows remapped (t,b) -> (b,t))
    k_gemm<<<(B_ * T_ / 128) * (O_ / 128), 256, 0, stream>>>(
        Fb, WoutT, out, b_out, B_ * T_, O_, H_, H_, O_, 0, 1, 0, O_ / 128, B_ * T_ / 128);
}

// Round 3
// 717.346 us; speedup vs baseline: 1.1571x; 1.0221x over previous
//
#include <hip/hip_runtime.h>
#include <hip/hip_bf16.h>

// GLIFR forward, MI355X.
//   S(T,B,H) f32 = x @ W_iv                      (GEMM)
//   for chunk c in 0..9 (20 steps == DELAY):
//     if c>0: S[chunk c] += F[chunk c-1] @ W_lat (GEMM, split-K=4, atomic)
//     k_rec: per-(b,h) ASC/volt/firing x20 -> F bf16
//   out(B,T,O) = F @ w_out + b_out               (GEMM, split-K=2, atomic)
// GEMM: 128x128 tile, BK=64, 4 waves, global_load_lds w16 into linear LDS
// with XOR-chunk swizzle (pre-swizzled global source), XCD block swizzle.

#define B_ 64
#define T_ 200
#define I_ 512
#define H_ 2048
#define O_ 512
#define BH_ 131072
#define DELAY_ 20
#define DT_ 0.05f
#define RMEM_ 0.1f

typedef __bf16 bf16x8 __attribute__((ext_vector_type(8)));
typedef float f32x4 __attribute__((ext_vector_type(4)));

__device__ __forceinline__ unsigned short f2bf(float f) {
    unsigned int u = __builtin_bit_cast(unsigned int, f);
    u = (u + 0x7fff + ((u >> 16) & 1)) >> 16;
    return (unsigned short)u;
}

__device__ __forceinline__ void gload16(const void* g, void* l) {
    __builtin_amdgcn_global_load_lds(
        (const __attribute__((address_space(1))) unsigned int*)g,
        (__attribute__((address_space(3))) unsigned int*)l, 16, 0, 0);
}

// ---------- f32 -> bf16 (same layout) ----------
__global__ void k_cvt4(const float* __restrict__ in, unsigned short* __restrict__ out, int n4) {
    int i = blockIdx.x * 256 + threadIdx.x;
    if (i >= n4) return;
    float4 v = ((const float4*)in)[i];
    ushort4 o;
    o.x = f2bf(v.x); o.y = f2bf(v.y); o.z = f2bf(v.z); o.w = f2bf(v.w);
    ((ushort4*)out)[i] = o;
}

// ---------- f32 (R x C) -> bf16 transposed (C x R), 32x32 LDS tiles ----------
__global__ __launch_bounds__(256) void k_tcvt(const float* __restrict__ in,
                                              unsigned short* __restrict__ out, int R, int C) {
    __shared__ float t[32][33];
    int bx = blockIdx.x, by = blockIdx.y;
    int tx = threadIdx.x & 31, ty = threadIdx.x >> 5;
    #pragma unroll
    for (int r = 0; r < 32; r += 8)
        t[ty + r][tx] = in[(size_t)(by * 32 + ty + r) * C + bx * 32 + tx];
    __syncthreads();
    #pragma unroll
    for (int r = 0; r < 32; r += 8)
        out[(size_t)(bx * 32 + ty + r) * R + by * 32 + tx] = f2bf(t[tx][ty + r]);
}

// ---------- bf16 GEMM: C(MxN) op= A(MxK) * Bt(NxK)^T ----------
// amap/cmap==1: m -> (m&63)*200 + (m>>6).  atomicMode: unsafeAtomicAdd into C,
// bias added by split 0 only. 1D grid gx*gy*ksplit, XCD-swizzled.
__global__ __launch_bounds__(256) void k_gemm(
    const unsigned short* __restrict__ A, const unsigned short* __restrict__ Bt,
    float* __restrict__ C, const float* __restrict__ bias,
    int K, int lda, int ldc, int amap, int cmap, int ksplit, int atomicMode,
    int gx, int gy)
{
    __shared__ unsigned short As[128 * 64];   // 16 KB
    __shared__ unsigned short Bs[128 * 64];   // 16 KB

    const int nb = gx * gy * ksplit;
    const int hw = blockIdx.x;
    const int wid = (hw & 7) * (nb >> 3) + (hw >> 3);
    const int split = wid % ksplit;
    const int w2 = wid / ksplit;
    int bm, bn;
    if (gx <= gy) { bn = w2 % gx; bm = w2 / gx; }
    else          { bm = w2 % gy; bn = w2 / gy; }

    const int nkt = K >> 6;                // 64-wide K tiles
    const int kper = nkt / ksplit;
    const int kbase = split * kper;

    const int tid = threadIdx.x;
    const int lane = tid & 63, wave = tid >> 6;
    const int wr = (wave >> 1) * 64, wc = (wave & 1) * 64;
    const int fr = lane & 15, kg = lane >> 4;
    const int rx = fr & 7;                 // read-side row XOR key

    // staging: 1024 16B-slots per matrix; thread owns slots tid + it*256.
    // slot s = (row, cp); global chunk cg = cp ^ (row&7)  (pre-swizzled source)
    const unsigned short* Ap[4]; const unsigned short* Bp[4]; int ls[4];
    #pragma unroll
    for (int it = 0; it < 4; ++it) {
        int s = tid + it * 256;
        int row = s >> 3, cp = s & 7;
        int cg = cp ^ (row & 7);
        int gm = bm * 128 + row;
        int ar = (amap == 1) ? ((gm & 63) * 200 + (gm >> 6)) : gm;
        Ap[it] = A + (size_t)ar * lda + kbase * 64 + cg * 8;
        Bp[it] = Bt + (size_t)(bn * 128 + row) * K + kbase * 64 + cg * 8;
        ls[it] = s * 8;
    }

    f32x4 acc[4][4] = {};

    for (int kt = 0; kt < kper; ++kt) {
        const int ko = kt * 64;
        #pragma unroll
        for (int it = 0; it < 4; ++it) {
            gload16(Ap[it] + ko, &As[ls[it]]);
            gload16(Bp[it] + ko, &Bs[ls[it]]);
        }
        __syncthreads();

        #pragma unroll
        for (int kk = 0; kk < 2; ++kk) {
            bf16x8 af[4], bfr[4];
            const int ck = ((kk << 2) | kg);
            #pragma unroll
            for (int i = 0; i < 4; ++i) {
                af[i]  = *(const bf16x8*)(&As[(wr + i * 16 + fr) * 64 + (ck ^ rx) * 8]);
                bfr[i] = *(const bf16x8*)(&Bs[(wc + i * 16 + fr) * 64 + (ck ^ rx) * 8]);
            }
            #pragma unroll
            for (int i = 0; i < 4; ++i)
                #pragma unroll
                for (int j = 0; j < 4; ++j)
                    acc[i][j] = __builtin_amdgcn_mfma_f32_16x16x32_bf16(af[i], bfr[j], acc[i][j], 0, 0, 0);
        }
        __syncthreads();
    }

    const int addBias = (bias != nullptr) && (split == 0);
    #pragma unroll
    for (int i = 0; i < 4; ++i) {
        int rbase = bm * 128 + wr + i * 16 + kg * 4;
        #pragma unroll
        for (int j = 0; j < 4; ++j) {
            int col = bn * 128 + wc + j * 16 + fr;
            #pragma unroll
            for (int r = 0; r < 4; ++r) {
                int m = rbase + r;
                int cr = (cmap == 1) ? ((m & 63) * 200 + (m >> 6)) : m;
                float* cp = C + (size_t)cr * ldc + col;
                float v = acc[i][j][r];
                if (addBias) v += bias[col];
                if (atomicMode) unsafeAtomicAdd(cp, v);
                else *cp = v;
            }
        }
    }
}

// ---------- per-(b,h) recurrence over one chunk ----------
__global__ __launch_bounds__(256) void k_rec(
    const float* __restrict__ S, unsigned short* __restrict__ F,
    float* __restrict__ volt, float* __restrict__ fire, float* __restrict__ asc,
    const float* __restrict__ thresh, const float* __restrict__ km,
    const float* __restrict__ asc_amp, const float* __restrict__ asc_r,
    const float* __restrict__ asc_k, int t0, int nsteps)
{
    int idx = blockIdx.x * 256 + threadIdx.x;
    int h = idx & (H_ - 1);
    float v = volt[idx], f = fire[idx];
    float a0 = asc[idx], a1 = asc[BH_ + idx];
    float th = thresh[h], k = km[h];
    float amp0 = asc_amp[h], amp1 = asc_amp[H_ + h];
    float r0 = asc_r[h], r1 = asc_r[H_ + h];
    float d0 = expf(-DT_ * asc_k[h]), d1 = expf(-DT_ * asc_k[H_ + h]);
    const float dtk = DT_ * k;
    for (int t = 0; t < nsteps; ++t) {
        float syn = S[(size_t)(t0 + t) * BH_ + idx];
        float na0 = a0 * d0 + f * (r0 * a0 + amp0);
        float na1 = a1 * d1 + f * (r1 * a1 + amp1);
        a0 = na0; a1 = na1;
        float tot = syn + a0 + a1;
        v = v * (1.f - f);
        v = v + dtk * (RMEM_ * tot - v);
        f = 1.f / (1.f + expf(-(v - th)));
        F[(size_t)(t0 + t) * BH_ + idx] = f2bf(f);
    }
    volt[idx] = v; fire[idx] = f;
    asc[idx] = a0; asc[BH_ + idx] = a1;
}

extern "C" void kernel_launch(void* const* d_in, const int* in_sizes, int n_in,
                              void* d_out, int out_size, void* d_ws, size_t ws_size,
                              hipStream_t stream) {
    const float* x       = (const float*)d_in[0];
    const float* w_iv    = (const float*)d_in[1];
    const float* w_lat   = (const float*)d_in[2];
    const float* thresh  = (const float*)d_in[3];
    const float* km      = (const float*)d_in[4];
    const float* asc_amp = (const float*)d_in[5];
    const float* asc_r   = (const float*)d_in[6];
    const float* asc_k   = (const float*)d_in[7];
    const float* w_out   = (const float*)d_in[8];
    const float* b_out   = (const float*)d_in[9];
    float* out = (float*)d_out;

    char* ws = (char*)d_ws;
    float*          S     = (float*)ws;                                   // (T,B,H) f32
    unsigned short* Fb    = (unsigned short*)(ws + 104857600);            // (T,B,H) bf16
    unsigned short* xb    = (unsigned short*)(ws + 157286400);            // x bf16
    unsigned short* WivT  = (unsigned short*)(ws + 170393600);            // (H,I)
    unsigned short* WlatT = (unsigned short*)(ws + 172490752);            // (H,H)
    unsigned short* WoutT = (unsigned short*)(ws + 180879360);            // (O,H)
    float*          volt  = (float*)(ws + 182976512);
    float*          fire  = (float*)(ws + 183500800);
    float*          asc   = (float*)(ws + 184025088);

    k_cvt4<<<6400, 256, 0, stream>>>(x, xb, (B_ * T_ * I_) / 4);
    k_tcvt<<<dim3(H_ / 32, I_ / 32), 256, 0, stream>>>(w_iv, WivT, I_, H_);
    k_tcvt<<<dim3(H_ / 32, H_ / 32), 256, 0, stream>>>(w_lat, WlatT, H_, H_);
    k_tcvt<<<dim3(O_ / 32, H_ / 32), 256, 0, stream>>>(w_out, WoutT, H_, O_);

    // zero state + zero out (atomic accumulation target)
    hipMemsetAsync(volt, 0, 524288 + 524288 + 1048576, stream);
    hipMemsetAsync(out, 0, (size_t)B_ * T_ * O_ * 4, stream);

    // S = x @ W_iv : grid 16*100 = 1600 blocks
    k_gemm<<<(B_ * T_ / 128) * (H_ / 128), 256, 0, stream>>>(
        xb, WivT, S, nullptr, I_, I_, H_, 1, 0, 1, 0, H_ / 128, B_ * T_ / 128);

    for (int c = 0; c < T_ / DELAY_; ++c) {
        if (c) {
            // S[chunk] += F[chunk-1] @ W_lat : split-K=4, 640 blocks, atomic
            k_gemm<<<(DELAY_ * B_ / 128) * (H_ / 128) * 4, 256, 0, stream>>>(
                Fb + (size_t)(c - 1) * DELAY_ * BH_, WlatT,
                S + (size_t)c * DELAY_ * BH_, nullptr,
                H_, H_, H_, 0, 0, 4, 1, H_ / 128, DELAY_ * B_ / 128);
        }
        k_rec<<<BH_ / 256, 256, 0, stream>>>(S, Fb, volt, fire, asc,
                                             thresh, km, asc_amp, asc_r, asc_k,
                                             c * DELAY_, DELAY_);
    }

    // out = F @ w_out + b_out : split-K=2, 800 blocks, atomic into zeroed out
    k_gemm<<<(B_ * T_ / 128) * (O_ / 128) * 2, 256, 0, stream>>>(
        Fb, WoutT, out, b_out, H_, H_, O_, 0, 1, 2, 1, O_ / 128, B_ * T_ / 128);
}

// Round 4
// 450.376 us; speedup vs baseline: 1.8431x; 1.5928x over previous
//
#include <hip/hip_runtime.h>
#include <hip/hip_bf16.h>

// GLIFR forward, MI355X.
//   S(T,B,H) f32 = x @ W_iv                      (GEMM 128x128, 1600 blocks)
//   for chunk c in 0..9 (20 steps == DELAY):
//     if c>0: S[chunk c] += F[chunk c-1] @ W_lat (GEMM 64x64, 640 blocks, beta=1)
//     k_rec: per-(b,h) ASC/volt/firing x20 -> F bf16
//   out(B,T,O) = F @ w_out + b_out               (GEMM 128x64, 800 blocks, bias)
// GEMM: double-buffered LDS, BK=64, 4 waves (2x2), global_load_lds w16,
// XOR-chunk swizzle (conflict-free, verified 0 conflicts), early-issue
// staging (next K-tile issued before current compute), XCD block swizzle.

#define B_ 64
#define T_ 200
#define I_ 512
#define H_ 2048
#define O_ 512
#define BH_ 131072
#define DELAY_ 20
#define DT_ 0.05f
#define RMEM_ 0.1f

typedef __bf16 bf16x8 __attribute__((ext_vector_type(8)));
typedef float f32x4 __attribute__((ext_vector_type(4)));

__device__ __forceinline__ unsigned short f2bf(float f) {
    unsigned int u = __builtin_bit_cast(unsigned int, f);
    u = (u + 0x7fff + ((u >> 16) & 1)) >> 16;
    return (unsigned short)u;
}

__device__ __forceinline__ void gload16(const void* g, void* l) {
    __builtin_amdgcn_global_load_lds(
        (const __attribute__((address_space(1))) unsigned int*)g,
        (__attribute__((address_space(3))) unsigned int*)l, 16, 0, 0);
}

// ---------- f32 -> bf16 (same layout) ----------
__global__ void k_cvt4(const float* __restrict__ in, unsigned short* __restrict__ out, int n4) {
    int i = blockIdx.x * 256 + threadIdx.x;
    if (i >= n4) return;
    float4 v = ((const float4*)in)[i];
    ushort4 o;
    o.x = f2bf(v.x); o.y = f2bf(v.y); o.z = f2bf(v.z); o.w = f2bf(v.w);
    ((ushort4*)out)[i] = o;
}

// ---------- f32 (R x C) -> bf16 transposed (C x R), 32x32 LDS tiles ----------
__global__ __launch_bounds__(256) void k_tcvt(const float* __restrict__ in,
                                              unsigned short* __restrict__ out, int R, int C) {
    __shared__ float t[32][33];
    int bx = blockIdx.x, by = blockIdx.y;
    int tx = threadIdx.x & 31, ty = threadIdx.x >> 5;
    #pragma unroll
    for (int r = 0; r < 32; r += 8)
        t[ty + r][tx] = in[(size_t)(by * 32 + ty + r) * C + bx * 32 + tx];
    __syncthreads();
    #pragma unroll
    for (int r = 0; r < 32; r += 8)
        out[(size_t)(bx * 32 + ty + r) * R + by * 32 + tx] = f2bf(t[tx][ty + r]);
}

// ---------- bf16 GEMM: C(MxN) = [C +] A(MxK) * Bt(NxK)^T [+ bias] ----------
// amap/cmap==1: m -> (m&63)*200 + (m>>6)   ((t,b) row <-> (b,t) row)
// Double-buffered LDS, early-issue staging. 1D grid gx*gy, XCD-swizzled.
template<int BM, int BN>
__global__ __launch_bounds__(256) void k_gemm(
    const unsigned short* __restrict__ A, const unsigned short* __restrict__ Bt,
    float* __restrict__ C, const float* __restrict__ bias,
    int K, int lda, int ldc, int amap, int cmap, int beta, int gx, int gy)
{
    constexpr int AIT = BM / 32, BIT = BN / 32;      // 16B chunks per thread
    constexpr int WTM = BM / 2, WTN = BN / 2;        // 2x2 wave grid
    constexpr int FM = WTM / 16, FN = WTN / 16;
    __shared__ unsigned short As[2 * BM * 64];
    __shared__ unsigned short Bs[2 * BN * 64];

    const int nb = gx * gy;
    const int hw = blockIdx.x;
    const int wid = (hw & 7) * (nb >> 3) + (hw >> 3);
    int bm, bn;
    if (gx <= gy) { bn = wid % gx; bm = wid / gx; }
    else          { bm = wid % gy; bn = wid / gy; }

    const int tid = threadIdx.x;
    const int lane = tid & 63, wave = tid >> 6;
    const int wr = (wave >> 1) * WTM, wc = (wave & 1) * WTN;
    const int fr = lane & 15, kg = lane >> 4;
    const int rx = fr & 7;

    // staging source pointers: slot s = (row, cp); global chunk cg = cp^(row&7)
    const unsigned short* Ap[AIT]; int lsA[AIT];
    #pragma unroll
    for (int it = 0; it < AIT; ++it) {
        int s = tid + it * 256;
        int row = s >> 3, cp = s & 7, cg = cp ^ (row & 7);
        int gm = bm * BM + row;
        int ar = amap ? ((gm & 63) * 200 + (gm >> 6)) : gm;
        Ap[it] = A + (size_t)ar * lda + cg * 8;
        lsA[it] = s * 8;
    }
    const unsigned short* Bp[BIT]; int lsB[BIT];
    #pragma unroll
    for (int it = 0; it < BIT; ++it) {
        int s = tid + it * 256;
        int row = s >> 3, cp = s & 7, cg = cp ^ (row & 7);
        Bp[it] = Bt + (size_t)(bn * BN + row) * K + cg * 8;
        lsB[it] = s * 8;
    }

    auto stage = [&](int buf, int kt) {
        const int ko = kt * 64;
        #pragma unroll
        for (int it = 0; it < AIT; ++it)
            gload16(Ap[it] + ko, &As[buf * BM * 64 + lsA[it]]);
        #pragma unroll
        for (int it = 0; it < BIT; ++it)
            gload16(Bp[it] + ko, &Bs[buf * BN * 64 + lsB[it]]);
    };

    f32x4 acc[FM][FN] = {};
    const int nk = K >> 6;

    stage(0, 0);
    __syncthreads();
    for (int kt = 0; kt < nk; ++kt) {
        const int cur = kt & 1;
        if (kt + 1 < nk) stage(cur ^ 1, kt + 1);   // issue async loads first
        #pragma unroll
        for (int kk = 0; kk < 2; ++kk) {
            const int ck = (kk << 2) | kg;
            bf16x8 af[FM], bfr[FN];
            #pragma unroll
            for (int i = 0; i < FM; ++i)
                af[i] = *(const bf16x8*)(&As[cur * BM * 64 + (wr + i * 16 + fr) * 64 + ((ck ^ rx) << 3)]);
            #pragma unroll
            for (int j = 0; j < FN; ++j)
                bfr[j] = *(const bf16x8*)(&Bs[cur * BN * 64 + (wc + j * 16 + fr) * 64 + ((ck ^ rx) << 3)]);
            #pragma unroll
            for (int i = 0; i < FM; ++i)
                #pragma unroll
                for (int j = 0; j < FN; ++j)
                    acc[i][j] = __builtin_amdgcn_mfma_f32_16x16x32_bf16(af[i], bfr[j], acc[i][j], 0, 0, 0);
        }
        __syncthreads();   // drains vmcnt (next tile staged) + frees cur buf
    }

    #pragma unroll
    for (int i = 0; i < FM; ++i) {
        int rbase = bm * BM + wr + i * 16 + kg * 4;
        #pragma unroll
        for (int j = 0; j < FN; ++j) {
            int col = bn * BN + wc + j * 16 + fr;
            #pragma unroll
            for (int r = 0; r < 4; ++r) {
                int m = rbase + r;
                int cr = cmap ? ((m & 63) * 200 + (m >> 6)) : m;
                float* cp = C + (size_t)cr * ldc + col;
                float v = acc[i][j][r];
                if (beta) v += *cp;
                if (bias) v += bias[col];
                *cp = v;
            }
        }
    }
}

// ---------- per-(b,h) recurrence over one chunk ----------
__global__ __launch_bounds__(256) void k_rec(
    const float* __restrict__ S, unsigned short* __restrict__ F,
    float* __restrict__ volt, float* __restrict__ fire, float* __restrict__ asc,
    const float* __restrict__ thresh, const float* __restrict__ km,
    const float* __restrict__ asc_amp, const float* __restrict__ asc_r,
    const float* __restrict__ asc_k, int t0, int nsteps)
{
    int idx = blockIdx.x * 256 + threadIdx.x;
    int h = idx & (H_ - 1);
    float v = volt[idx], f = fire[idx];
    float a0 = asc[idx], a1 = asc[BH_ + idx];
    float th = thresh[h], k = km[h];
    float amp0 = asc_amp[h], amp1 = asc_amp[H_ + h];
    float r0 = asc_r[h], r1 = asc_r[H_ + h];
    float d0 = expf(-DT_ * asc_k[h]), d1 = expf(-DT_ * asc_k[H_ + h]);
    const float dtk = DT_ * k;
    for (int t = 0; t < nsteps; ++t) {
        float syn = S[(size_t)(t0 + t) * BH_ + idx];
        float na0 = a0 * d0 + f * (r0 * a0 + amp0);
        float na1 = a1 * d1 + f * (r1 * a1 + amp1);
        a0 = na0; a1 = na1;
        float tot = syn + a0 + a1;
        v = v * (1.f - f);
        v = v + dtk * (RMEM_ * tot - v);
        f = 1.f / (1.f + expf(-(v - th)));
        F[(size_t)(t0 + t) * BH_ + idx] = f2bf(f);
    }
    volt[idx] = v; fire[idx] = f;
    asc[idx] = a0; asc[BH_ + idx] = a1;
}

extern "C" void kernel_launch(void* const* d_in, const int* in_sizes, int n_in,
                              void* d_out, int out_size, void* d_ws, size_t ws_size,
                              hipStream_t stream) {
    const float* x       = (const float*)d_in[0];
    const float* w_iv    = (const float*)d_in[1];
    const float* w_lat   = (const float*)d_in[2];
    const float* thresh  = (const float*)d_in[3];
    const float* km      = (const float*)d_in[4];
    const float* asc_amp = (const float*)d_in[5];
    const float* asc_r   = (const float*)d_in[6];
    const float* asc_k   = (const float*)d_in[7];
    const float* w_out   = (const float*)d_in[8];
    const float* b_out   = (const float*)d_in[9];
    float* out = (float*)d_out;

    char* ws = (char*)d_ws;
    float*          S     = (float*)ws;                                   // (T,B,H) f32
    unsigned short* Fb    = (unsigned short*)(ws + 104857600);            // (T,B,H) bf16
    unsigned short* xb    = (unsigned short*)(ws + 157286400);            // x bf16
    unsigned short* WivT  = (unsigned short*)(ws + 170393600);            // (H,I)
    unsigned short* WlatT = (unsigned short*)(ws + 172490752);            // (H,H)
    unsigned short* WoutT = (unsigned short*)(ws + 180879360);            // (O,H)
    float*          volt  = (float*)(ws + 182976512);
    float*          fire  = (float*)(ws + 183500800);
    float*          asc   = (float*)(ws + 184025088);

    k_cvt4<<<6400, 256, 0, stream>>>(x, xb, (B_ * T_ * I_) / 4);
    k_tcvt<<<dim3(H_ / 32, I_ / 32), 256, 0, stream>>>(w_iv, WivT, I_, H_);
    k_tcvt<<<dim3(H_ / 32, H_ / 32), 256, 0, stream>>>(w_lat, WlatT, H_, H_);
    k_tcvt<<<dim3(O_ / 32, H_ / 32), 256, 0, stream>>>(w_out, WoutT, H_, O_);

    hipMemsetAsync(volt, 0, 524288 + 524288 + 1048576, stream);

    // S = x @ W_iv : 100x16 = 1600 blocks
    k_gemm<128, 128><<<(B_ * T_ / 128) * (H_ / 128), 256, 0, stream>>>(
        xb, WivT, S, nullptr, I_, I_, H_, 1, 0, 0, H_ / 128, B_ * T_ / 128);

    for (int c = 0; c < T_ / DELAY_; ++c) {
        if (c) {
            // S[chunk] += F[chunk-1] @ W_lat : 20x32 = 640 blocks
            k_gemm<64, 64><<<(DELAY_ * B_ / 64) * (H_ / 64), 256, 0, stream>>>(
                Fb + (size_t)(c - 1) * DELAY_ * BH_, WlatT,
                S + (size_t)c * DELAY_ * BH_, nullptr,
                H_, H_, H_, 0, 0, 1, H_ / 64, DELAY_ * B_ / 64);
        }
        k_rec<<<BH_ / 256, 256, 0, stream>>>(S, Fb, volt, fire, asc,
                                             thresh, km, asc_amp, asc_r, asc_k,
                                             c * DELAY_, DELAY_);
    }

    // out = F @ w_out + b_out : 100x8 = 800 blocks
    k_gemm<128, 64><<<(B_ * T_ / 128) * (O_ / 64), 256, 0, stream>>>(
        Fb, WoutT, out, b_out, H_, H_, O_, 0, 1, 0, O_ / 64, B_ * T_ / 128);
}